// Round 1
// baseline (335.500 us; speedup 1.0000x reference)
//
#include <hip/hip_runtime.h>
#include <math.h>

typedef unsigned short u16;
typedef __attribute__((ext_vector_type(4))) float f32x4;
typedef __attribute__((ext_vector_type(8))) short bf16x8;

#define B_ 2
#define T_ 2048
#define H_ 16
#define HID 1024
#define NQKV 3072
#define M_ 4096

__device__ __forceinline__ u16 f2bf(float f) {
  union { float f; unsigned u; } v; v.f = f;
  unsigned r = v.u + 0x7FFFu + ((v.u >> 16) & 1u);
  return (u16)(r >> 16);
}
__device__ __forceinline__ float bf2f(u16 u) {
  union { unsigned u; float f; } v; v.u = ((unsigned)u) << 16; return v.f;
}

// ---------------- fp32 -> bf16 convert ----------------
__global__ void cvt_bf16(const float* __restrict__ in, u16* __restrict__ out, int n4) {
  int i = blockIdx.x * blockDim.x + threadIdx.x;
  if (i >= n4) return;
  float4 v = ((const float4*)in)[i];
  uint2 o;
  o.x = (unsigned)f2bf(v.x) | ((unsigned)f2bf(v.y) << 16);
  o.y = (unsigned)f2bf(v.z) | ((unsigned)f2bf(v.w) << 16);
  ((uint2*)out)[i] = o;
}

// ---------------- NT GEMM: C[m,n] = sum_k A[m,k]*Bt[n,k] + bias[n] ----------------
// A: [M][K] bf16, Bt: [N][K] bf16. 128x128 tile, BK=32, 4 waves (2x2 of 64x64).
template<int OUT_BF16>
__global__ __launch_bounds__(256) void gemm_nt(const u16* __restrict__ A,
    const u16* __restrict__ Bt, const float* __restrict__ bias,
    void* __restrict__ outp, int M, int N, int K)
{
  __shared__ u16 lsA[128 * 40];  // rows padded to 40 elems (80B, 16B-aligned, 2-way banks)
  __shared__ u16 lsB[128 * 40];
  const int t = threadIdx.x;
  const int l = t & 63, w = t >> 6;
  const int wm = (w >> 1) * 64, wn = (w & 1) * 64;
  const int lr = l & 15, lg = l >> 4;
  const long bm = (long)blockIdx.y * 128, bn = (long)blockIdx.x * 128;

  f32x4 acc[4][4];
#pragma unroll
  for (int i = 0; i < 4; i++)
#pragma unroll
    for (int j = 0; j < 4; j++) acc[i][j] = (f32x4){0.f, 0.f, 0.f, 0.f};

  const int r0 = t >> 2, o0 = (t & 3) * 8;  // chunk t      (rows 0..63)
  const int r1 = r0 + 64;                   // chunk t+256  (rows 64..127)

  for (int k0 = 0; k0 < K; k0 += 32) {
    if (k0) __syncthreads();
    *(int4*)&lsA[r0 * 40 + o0] = *(const int4*)&A[(bm + r0) * (long)K + k0 + o0];
    *(int4*)&lsA[r1 * 40 + o0] = *(const int4*)&A[(bm + r1) * (long)K + k0 + o0];
    *(int4*)&lsB[r0 * 40 + o0] = *(const int4*)&Bt[(bn + r0) * (long)K + k0 + o0];
    *(int4*)&lsB[r1 * 40 + o0] = *(const int4*)&Bt[(bn + r1) * (long)K + k0 + o0];
    __syncthreads();
    bf16x8 af[4], bfv[4];
#pragma unroll
    for (int mi = 0; mi < 4; mi++)
      af[mi] = *(const bf16x8*)&lsA[(wm + mi * 16 + lr) * 40 + lg * 8];
#pragma unroll
    for (int ni = 0; ni < 4; ni++)
      bfv[ni] = *(const bf16x8*)&lsB[(wn + ni * 16 + lr) * 40 + lg * 8];
#pragma unroll
    for (int mi = 0; mi < 4; mi++)
#pragma unroll
      for (int ni = 0; ni < 4; ni++)
        acc[mi][ni] = __builtin_amdgcn_mfma_f32_16x16x32_bf16(af[mi], bfv[ni], acc[mi][ni], 0, 0, 0);
  }
  // epilogue: D[row=(l>>4)*4+r][col=l&15]
#pragma unroll
  for (int mi = 0; mi < 4; mi++)
#pragma unroll
    for (int ni = 0; ni < 4; ni++) {
      long row = bm + wm + mi * 16 + lg * 4;
      long col = bn + wn + ni * 16 + lr;
      float bv = bias[col];
#pragma unroll
      for (int r = 0; r < 4; r++) {
        float v = acc[mi][ni][r] + bv;
        if (OUT_BF16) ((u16*)outp)[(row + r) * (long)N + col] = f2bf(v);
        else          ((float*)outp)[(row + r) * (long)N + col] = v;
      }
    }
}

// ---------------- RoPE on q,k; scatter to (b,h,t,d) bf16 ----------------
__global__ void rope_qk(const u16* __restrict__ qkv, u16* __restrict__ Q, u16* __restrict__ K) {
  int idx = blockIdx.x * 256 + threadIdx.x;   // one thread per (m, h)
  int h = idx & 15;
  int m = idx >> 4;          // b*T + t
  int tpos = m & (T_ - 1);
  int b = m >> 11;
  const u16* qr = qkv + (long)m * NQKV + h * 64;
  alignas(16) u16 qv[64];
  alignas(16) u16 kv[64];
#pragma unroll
  for (int c = 0; c < 8; c++) {
    *(int4*)&qv[c * 8] = *(const int4*)&qr[c * 8];
    *(int4*)&kv[c * 8] = *(const int4*)&qr[1024 + c * 8];
  }
#pragma unroll
  for (int i = 0; i < 16; i++) {
    float inv = powf(10000.f, -(float)i * (1.f / 16.f));
    float ang = (float)tpos * inv;
    float s, c;
    sincosf(ang, &s, &c);
    float q1 = bf2f(qv[2 * i]), q2 = bf2f(qv[2 * i + 1]);
    qv[2 * i]     = f2bf(q1 * c - q2 * s);
    qv[2 * i + 1] = f2bf(q1 * s + q2 * c);
    float k1 = bf2f(kv[2 * i]), k2 = bf2f(kv[2 * i + 1]);
    kv[2 * i]     = f2bf(k1 * c - k2 * s);
    kv[2 * i + 1] = f2bf(k1 * s + k2 * c);
  }
  long ob = ((long)(b * 16 + h) * T_ + tpos) * 64;
#pragma unroll
  for (int c = 0; c < 8; c++) {
    *(int4*)&Q[ob + c * 8] = *(int4*)&qv[c * 8];
    *(int4*)&K[ob + c * 8] = *(int4*)&kv[c * 8];
  }
}

// ---------------- V transpose: qkv v-block -> Vt (b,h,d,t) bf16 ----------------
__global__ __launch_bounds__(256) void v_trans(const u16* __restrict__ qkv, u16* __restrict__ Vt) {
  int tt = blockIdx.x, bh = blockIdx.y;
  int b = bh >> 4, h = bh & 15;
  __shared__ u16 ls[64 * 72];
  int t = threadIdx.x;
  for (int c = t; c < 512; c += 256) {
    int row = c >> 3, off = (c & 7) * 8;
    *(int4*)&ls[row * 72 + off] =
        *(const int4*)&qkv[((long)(b * T_ + tt * 64 + row)) * NQKV + 2048 + h * 64 + off];
  }
  __syncthreads();
  for (int c = t; c < 512; c += 256) {
    int d = c >> 3, toff = (c & 7) * 8;
    alignas(16) u16 tmp[8];
#pragma unroll
    for (int j = 0; j < 8; j++) tmp[j] = ls[(toff + j) * 72 + d];
    *(int4*)&Vt[((long)(bh * 64 + d)) * T_ + tt * 64 + toff] = *(int4*)tmp;
  }
}

// ---------------- causal flash attention ----------------
// grid (T/64, B*H), 256 thr. Wave w owns q-rows [qt*64+w*16, +16). Online softmax fp32.
__global__ __launch_bounds__(256) void fattn(const u16* __restrict__ Q, const u16* __restrict__ K,
                                             const u16* __restrict__ V, u16* __restrict__ O) {
  const int qt = blockIdx.x, bh = blockIdx.y;
  __shared__ u16 lsK[64 * 72];
  __shared__ u16 lsV[64 * 72];
  __shared__ u16 lsP[4 * 16 * 72];
  const int t = threadIdx.x, l = t & 63, w = t >> 6;
  const int lr = l & 15, lg = l >> 4;
  const u16* Qb = Q + (long)bh * T_ * 64;
  const u16* Kb = K + (long)bh * T_ * 64;
  const u16* Vb = V + (long)bh * 64 * T_;
  u16* lsPw = lsP + w * 16 * 72;

  bf16x8 aq[2];
#pragma unroll
  for (int ks = 0; ks < 2; ks++)
    aq[ks] = *(const bf16x8*)&Qb[((long)(qt * 64 + w * 16 + lr)) * 64 + ks * 32 + lg * 8];

  f32x4 o[4];
#pragma unroll
  for (int di = 0; di < 4; di++) o[di] = (f32x4){0.f, 0.f, 0.f, 0.f};
  float mrow[4] = {-INFINITY, -INFINITY, -INFINITY, -INFINITY};
  float lrow[4] = {0.f, 0.f, 0.f, 0.f};

  for (int kt = 0; kt <= qt; kt++) {
    __syncthreads();
    {
      int row0 = t >> 3, off0 = (t & 7) * 8;
      *(int4*)&lsK[row0 * 72 + off0] = *(const int4*)&Kb[((long)(kt * 64 + row0)) * 64 + off0];
      *(int4*)&lsV[row0 * 72 + off0] = *(const int4*)&Vb[(long)row0 * T_ + kt * 64 + off0];
      int row1 = row0 + 32;
      *(int4*)&lsK[row1 * 72 + off0] = *(const int4*)&Kb[((long)(kt * 64 + row1)) * 64 + off0];
      *(int4*)&lsV[row1 * 72 + off0] = *(const int4*)&Vb[(long)row1 * T_ + kt * 64 + off0];
    }
    __syncthreads();

    f32x4 s[4];
#pragma unroll
    for (int ji = 0; ji < 4; ji++) s[ji] = (f32x4){0.f, 0.f, 0.f, 0.f};
#pragma unroll
    for (int ks = 0; ks < 2; ks++)
#pragma unroll
      for (int ji = 0; ji < 4; ji++) {
        bf16x8 kb = *(const bf16x8*)&lsK[(ji * 16 + lr) * 72 + ks * 32 + lg * 8];
        s[ji] = __builtin_amdgcn_mfma_f32_16x16x32_bf16(aq[ks], kb, s[ji], 0, 0, 0);
      }

#pragma unroll
    for (int r = 0; r < 4; r++) {
      const int rowg = qt * 64 + w * 16 + lg * 4 + r;
      float pr[4], mx = -INFINITY;
#pragma unroll
      for (int ji = 0; ji < 4; ji++) {
        int colg = kt * 64 + ji * 16 + lr;
        float sv = s[ji][r] * 0.125f;
        if (colg > rowg) sv = -1e9f;
        pr[ji] = sv;
        mx = fmaxf(mx, sv);
      }
#pragma unroll
      for (int mk = 1; mk < 16; mk <<= 1) mx = fmaxf(mx, __shfl_xor(mx, mk, 64));
      float newm = fmaxf(mrow[r], mx);
      float sf = expf(mrow[r] - newm);
      float rs = 0.f;
#pragma unroll
      for (int ji = 0; ji < 4; ji++) {
        float p = expf(pr[ji] - newm);
        rs += p;
        lsPw[(lg * 4 + r) * 72 + ji * 16 + lr] = f2bf(p);
      }
#pragma unroll
      for (int mk = 1; mk < 16; mk <<= 1) rs += __shfl_xor(rs, mk, 64);
      mrow[r] = newm;
      lrow[r] = lrow[r] * sf + rs;
#pragma unroll
      for (int di = 0; di < 4; di++) o[di][r] *= sf;
    }

#pragma unroll
    for (int js = 0; js < 2; js++) {
      bf16x8 pa = *(const bf16x8*)&lsPw[lr * 72 + js * 32 + lg * 8];
#pragma unroll
      for (int di = 0; di < 4; di++) {
        bf16x8 vb = *(const bf16x8*)&lsV[(di * 16 + lr) * 72 + js * 32 + lg * 8];
        o[di] = __builtin_amdgcn_mfma_f32_16x16x32_bf16(pa, vb, o[di], 0, 0, 0);
      }
    }
  }

  const int b = bh >> 4, h = bh & 15;
#pragma unroll
  for (int di = 0; di < 4; di++)
#pragma unroll
    for (int r = 0; r < 4; r++) {
      long rowt = (long)(b * T_ + qt * 64 + w * 16 + lg * 4 + r);
      O[rowt * 1024 + h * 64 + di * 16 + lr] = f2bf(o[di][r] / lrow[r]);
    }
}

extern "C" void kernel_launch(void* const* d_in, const int* in_sizes, int n_in,
                              void* d_out, int out_size, void* d_ws, size_t ws_size,
                              hipStream_t stream) {
  (void)in_sizes; (void)n_in; (void)out_size; (void)ws_size;
  const float* x     = (const float*)d_in[0];
  // d_in[1] = mask: deterministic causal triu — applied analytically, not read.
  const float* qkv_w = (const float*)d_in[2];
  const float* qkv_b = (const float*)d_in[3];
  const float* out_w = (const float*)d_in[4];
  const float* out_b = (const float*)d_in[5];
  char* ws = (char*)d_ws;
  size_t off = 0;
  auto alloc = [&](size_t n) { void* p = ws + off; off += (n + 255) & ~(size_t)255; return p; };
  u16* xb    = (u16*)alloc((size_t)M_ * HID * 2);
  u16* wqkv  = (u16*)alloc((size_t)NQKV * HID * 2);
  u16* wout  = (u16*)alloc((size_t)HID * HID * 2);
  u16* qkvb  = (u16*)alloc((size_t)M_ * NQKV * 2);
  u16* Qb    = (u16*)alloc((size_t)M_ * HID * 2);
  u16* Kb    = (u16*)alloc((size_t)M_ * HID * 2);
  u16* Vtb   = (u16*)alloc((size_t)M_ * HID * 2);
  u16* attnb = (u16*)alloc((size_t)M_ * HID * 2);

  cvt_bf16<<<(M_ * HID / 4 + 255) / 256, 256, 0, stream>>>(x, xb, M_ * HID / 4);
  cvt_bf16<<<(NQKV * HID / 4 + 255) / 256, 256, 0, stream>>>(qkv_w, wqkv, NQKV * HID / 4);
  cvt_bf16<<<(HID * HID / 4 + 255) / 256, 256, 0, stream>>>(out_w, wout, HID * HID / 4);
  gemm_nt<1><<<dim3(NQKV / 128, M_ / 128), 256, 0, stream>>>(xb, wqkv, qkv_b, qkvb, M_, NQKV, HID);
  rope_qk<<<(B_ * T_ * H_) / 256, 256, 0, stream>>>(qkvb, Qb, Kb);
  v_trans<<<dim3(T_ / 64, B_ * H_), 256, 0, stream>>>(qkvb, Vtb);
  fattn<<<dim3(T_ / 64, B_ * H_), 256, 0, stream>>>(Qb, Kb, Vtb, attnb);
  gemm_nt<0><<<dim3(HID / 128, M_ / 128), 256, 0, stream>>>(attnb, wout, out_b, (float*)d_out, M_, HID, HID);
}

// Round 2
// 223.359 us; speedup vs baseline: 1.5021x; 1.5021x over previous
//
#include <hip/hip_runtime.h>
#include <math.h>

typedef unsigned short u16;
typedef unsigned int u32;
typedef __attribute__((ext_vector_type(4))) float f32x4;
typedef __attribute__((ext_vector_type(8))) short bf16x8;

#define B_ 2
#define T_ 2048
#define H_ 16
#define HID 1024
#define NQKV 3072
#define M_ 4096

__device__ __forceinline__ u16 f2bf(float f) {
  union { float f; unsigned u; } v; v.f = f;
  unsigned r = v.u + 0x7FFFu + ((v.u >> 16) & 1u);
  return (u16)(r >> 16);
}
__device__ __forceinline__ float bf2f(u16 u) {
  union { unsigned u; float f; } v; v.u = ((unsigned)u) << 16; return v.f;
}

// async global->LDS, 16B per lane; LDS dest = wave-uniform base + lane*16
__device__ __forceinline__ void gload16(const void* g, void* l) {
  __builtin_amdgcn_global_load_lds((const __attribute__((address_space(1))) void*)g,
                                   (__attribute__((address_space(3))) void*)l, 16, 0, 0);
}

// ---------------- fp32 -> bf16 convert ----------------
__global__ void cvt_bf16(const float* __restrict__ in, u16* __restrict__ out, int n4) {
  int i = blockIdx.x * blockDim.x + threadIdx.x;
  if (i >= n4) return;
  float4 v = ((const float4*)in)[i];
  uint2 o;
  o.x = (unsigned)f2bf(v.x) | ((unsigned)f2bf(v.y) << 16);
  o.y = (unsigned)f2bf(v.z) | ((unsigned)f2bf(v.w) << 16);
  ((uint2*)out)[i] = o;
}

// ---------------- RoPE cos/sin table: tab[t*16+f] = {cos, sin} ----------------
__global__ void rope_tab(float* __restrict__ tab) {
  int i = blockIdx.x * 256 + threadIdx.x;  // T*16
  int tpos = i >> 4, f = i & 15;
  // inv_freq = 10000^(-f/16) = exp2(-f * log2(10000)/16)
  float ang = (float)tpos * exp2f(-(float)f * 0.83048202372184058696f);
  float s, c;
  sincosf(ang, &s, &c);
  tab[i * 2] = c;
  tab[i * 2 + 1] = s;
}

// ---------------- NT GEMM (m97 structure): C[m,n] = A[m,:]*Bt[n,:] + bias[n] ----------------
// A:[M][K] bf16, Bt:[N][K] bf16. 128x128 tile, BK=32, 4 waves (2x2 of 64x64),
// global_load_lds dwordx4 staging into linear [128][32] LDS (bank-even for b128 reads).
template<int OUT_BF16>
__global__ __launch_bounds__(256) void gemm_nt(const u16* __restrict__ A,
    const u16* __restrict__ Bt, const float* __restrict__ bias,
    void* __restrict__ outp, int N, int K)
{
  __shared__ u16 lsA[128 * 32];
  __shared__ u16 lsB[128 * 32];
  const int t = threadIdx.x;
  const int l = t & 63, w = t >> 6;
  const int wm = (w >> 1) * 64, wn = (w & 1) * 64;
  const int lr = l & 15, lg = l >> 4;
  const long bm = (long)blockIdx.y * 128, bn = (long)blockIdx.x * 128;

  f32x4 acc[4][4];
#pragma unroll
  for (int i = 0; i < 4; i++)
#pragma unroll
    for (int j = 0; j < 4; j++) acc[i][j] = (f32x4){0.f, 0.f, 0.f, 0.f};

  // staging: slab = 16 rows x 32 k (1KB). wave w stages slabs {2w, 2w+1} of A and B.
  const int srow = l >> 2, sko = (l & 3) * 8;
  const u16* Ab = A + (bm + srow) * (long)K + sko;
  const u16* Bb = Bt + (bn + srow) * (long)K + sko;
  const int s0 = 2 * w, s1 = 2 * w + 1;

  for (int k0 = 0; k0 < K; k0 += 32) {
    if (k0) __syncthreads();
    gload16(Ab + (long)(s0 * 16) * K + k0, &lsA[s0 * 512]);
    gload16(Ab + (long)(s1 * 16) * K + k0, &lsA[s1 * 512]);
    gload16(Bb + (long)(s0 * 16) * K + k0, &lsB[s0 * 512]);
    gload16(Bb + (long)(s1 * 16) * K + k0, &lsB[s1 * 512]);
    __syncthreads();  // compiler drains vmcnt(0) here -> tiles landed
    bf16x8 af[4], bfv[4];
#pragma unroll
    for (int mi = 0; mi < 4; mi++)
      af[mi] = *(const bf16x8*)&lsA[(wm + mi * 16 + lr) * 32 + lg * 8];
#pragma unroll
    for (int ni = 0; ni < 4; ni++)
      bfv[ni] = *(const bf16x8*)&lsB[(wn + ni * 16 + lr) * 32 + lg * 8];
#pragma unroll
    for (int mi = 0; mi < 4; mi++)
#pragma unroll
      for (int ni = 0; ni < 4; ni++)
        acc[mi][ni] = __builtin_amdgcn_mfma_f32_16x16x32_bf16(af[mi], bfv[ni], acc[mi][ni], 0, 0, 0);
  }
#pragma unroll
  for (int mi = 0; mi < 4; mi++)
#pragma unroll
    for (int ni = 0; ni < 4; ni++) {
      long row = bm + wm + mi * 16 + lg * 4;
      long col = bn + wn + ni * 16 + lr;
      float bv = bias[col];
#pragma unroll
      for (int r = 0; r < 4; r++) {
        float v = acc[mi][ni][r] + bv;
        if (OUT_BF16) ((u16*)outp)[(row + r) * (long)N + col] = f2bf(v);
        else          ((float*)outp)[(row + r) * (long)N + col] = v;
      }
    }
}

// ---------------- RoPE on q,k; q scaled by 1/8 (folds attention scale); (b,h,t,d) bf16 ----------------
__global__ void rope_qk(const u16* __restrict__ qkv, const float* __restrict__ tab,
                        u16* __restrict__ Q, u16* __restrict__ K) {
  int idx = blockIdx.x * 256 + threadIdx.x;  // one thread per (m, h)
  int h = idx & 15;
  int m = idx >> 4;
  int tpos = m & (T_ - 1);
  int b = m >> 11;
  const u16* qr = qkv + (long)m * NQKV + h * 64;
  alignas(16) u16 qv[64];
  alignas(16) u16 kv[64];
#pragma unroll
  for (int c = 0; c < 8; c++) {
    *(int4*)&qv[c * 8] = *(const int4*)&qr[c * 8];
    *(int4*)&kv[c * 8] = *(const int4*)&qr[1024 + c * 8];
  }
#pragma unroll
  for (int i = 0; i < 16; i++) {
    float c = tab[(tpos * 16 + i) * 2];
    float s = tab[(tpos * 16 + i) * 2 + 1];
    float q1 = bf2f(qv[2 * i]), q2 = bf2f(qv[2 * i + 1]);
    qv[2 * i]     = f2bf((q1 * c - q2 * s) * 0.125f);
    qv[2 * i + 1] = f2bf((q1 * s + q2 * c) * 0.125f);
    float k1 = bf2f(kv[2 * i]), k2 = bf2f(kv[2 * i + 1]);
    kv[2 * i]     = f2bf(k1 * c - k2 * s);
    kv[2 * i + 1] = f2bf(k1 * s + k2 * c);
  }
#pragma unroll
  for (int j = 32; j < 64; j++) qv[j] = f2bf(bf2f(qv[j]) * 0.125f);  // exact exp shift
  long ob = ((long)(b * 16 + h) * T_ + tpos) * 64;
#pragma unroll
  for (int c = 0; c < 8; c++) {
    *(int4*)&Q[ob + c * 8] = *(int4*)&qv[c * 8];
    *(int4*)&K[ob + c * 8] = *(int4*)&kv[c * 8];
  }
}

// ---------------- V transpose: qkv v-block -> Vt (b,h,d,t) bf16 ----------------
__global__ __launch_bounds__(256) void v_trans(const u16* __restrict__ qkv, u16* __restrict__ Vt) {
  int tt = blockIdx.x, bh = blockIdx.y;
  int b = bh >> 4, h = bh & 15;
  __shared__ u16 ls[64 * 72];
  int t = threadIdx.x;
  for (int c = t; c < 512; c += 256) {
    int row = c >> 3, off = (c & 7) * 8;
    *(int4*)&ls[row * 72 + off] =
        *(const int4*)&qkv[((long)(b * T_ + tt * 64 + row)) * NQKV + 2048 + h * 64 + off];
  }
  __syncthreads();
  for (int c = t; c < 512; c += 256) {
    int d = c >> 3, toff = (c & 7) * 8;
    alignas(16) u16 tmp[8];
#pragma unroll
    for (int j = 0; j < 8; j++) tmp[j] = ls[(toff + j) * 72 + d];
    *(int4*)&Vt[((long)(bh * 64 + d)) * T_ + tt * 64 + toff] = *(int4*)tmp;
  }
}

// ---------------- causal flash attention, swapped-QK^T (S^T) formulation ----------------
// 1024 blocks (heavy qt first), 4 waves; wave w owns q-rows [qt*64+w*16, +16).
// Lane (lr,lg): q = w*16+lr (softmax state per-lane scalar), holds k-rows lg*4..+3 per 16-tile.
__global__ __launch_bounds__(256, 4) void fattn(const u16* __restrict__ Q, const u16* __restrict__ Kp,
                                                const u16* __restrict__ V, u16* __restrict__ O) {
  const int id = blockIdx.x;
  const int qt = 31 - (id >> 5);   // heavy blocks dispatched first
  const int bh = id & 31;
  __shared__ u16 lsK[64 * 64];     // [krow][d], XOR swizzle: u16col ^= (row&7)*8
  __shared__ u16 lsV[64 * 64];     // [d][k],  same swizzle
  __shared__ u32 lsP[4 * 16 * 36]; // per-wave P: 16 q-rows x 32 dwords (pad to 36)
  const int t = threadIdx.x, l = t & 63, w = t >> 6;
  const int lr = l & 15, lg = l >> 4;
  const u16* Qb = Q + (long)bh * T_ * 64;
  const u16* Kb = Kp + (long)bh * T_ * 64;
  const u16* Vb = V + (long)bh * 64 * T_;
  u32* lsPw = lsP + w * 576;

  bf16x8 aq[2];  // B-frag: row=q=lr, d=lg*8.. (Q pre-scaled by 1/8)
#pragma unroll
  for (int ks = 0; ks < 2; ks++)
    aq[ks] = *(const bf16x8*)&Qb[((long)(qt * 64 + w * 16 + lr)) * 64 + ks * 32 + lg * 8];

  f32x4 o[4];  // D[q=lg*4+r][d=di*16+lr]
#pragma unroll
  for (int di = 0; di < 4; di++) o[di] = (f32x4){0.f, 0.f, 0.f, 0.f};
  float mrow = -1e30f, lrow = 0.f;

  // staging geometry: slab = 8 rows x 128B = 1KB; wave w does slabs {2w,2w+1} of K and V.
  // pre-swizzled global source (m173): LDS chunk c holds src chunk c^(row&7).
  const int srow = l >> 3;             // row within slab (== row&7)
  const int scx = ((l & 7) ^ srow) * 8;  // swizzled source u16 chunk offset

  for (int kt = 0; kt <= qt; kt++) {
    if (kt) __syncthreads();
    const u16* kp = Kb + kt * 4096;
    const u16* vp = Vb + kt * 64;
    gload16(kp + (long)(16 * w + srow) * 64 + scx,       &lsK[(2 * w) * 512]);
    gload16(kp + (long)(16 * w + 8 + srow) * 64 + scx,   &lsK[(2 * w + 1) * 512]);
    gload16(vp + (long)(16 * w + srow) * T_ + scx,       &lsV[(2 * w) * 512]);
    gload16(vp + (long)(16 * w + 8 + srow) * T_ + scx,   &lsV[(2 * w + 1) * 512]);
    __syncthreads();  // vmcnt(0) drain -> tiles ready

    // S^T = K . Q^T : s[ji] holds rows k=ji*16+lg*4+r, col q=lr
    f32x4 s[4];
#pragma unroll
    for (int ji = 0; ji < 4; ji++) s[ji] = (f32x4){0.f, 0.f, 0.f, 0.f};
#pragma unroll
    for (int ks = 0; ks < 2; ks++)
#pragma unroll
      for (int ji = 0; ji < 4; ji++) {
        int row = ji * 16 + lr;
        bf16x8 kf = *(const bf16x8*)&lsK[row * 64 + ((ks * 32 + lg * 8) ^ ((row & 7) * 8))];
        s[ji] = __builtin_amdgcn_mfma_f32_16x16x32_bf16(kf, aq[ks], s[ji], 0, 0, 0);
      }

    if (kt == qt) {  // only the diagonal tile needs masking
      int qloc = w * 16 + lr;
#pragma unroll
      for (int ji = 0; ji < 4; ji++)
#pragma unroll
        for (int r = 0; r < 4; r++)
          if (ji * 16 + lg * 4 + r > qloc) s[ji][r] = -1e30f;
    }

    // softmax: 16 in-lane values + 2-shfl cross-lg reduce
    float mx = s[0][0];
#pragma unroll
    for (int ji = 0; ji < 4; ji++)
#pragma unroll
      for (int r = 0; r < 4; r++) mx = fmaxf(mx, s[ji][r]);
    mx = fmaxf(mx, __shfl_xor(mx, 16, 64));
    mx = fmaxf(mx, __shfl_xor(mx, 32, 64));
    bool grow = mx > mrow;
    float newm = fmaxf(mrow, mx);
    float rs = 0.f;
    u32 pd[8];
#pragma unroll
    for (int ji = 0; ji < 4; ji++)
#pragma unroll
      for (int hh = 0; hh < 2; hh++) {
        float p0 = __expf(s[ji][2 * hh] - newm);
        float p1 = __expf(s[ji][2 * hh + 1] - newm);
        rs += p0 + p1;
        pd[ji * 2 + hh] = (u32)f2bf(p0) | ((u32)f2bf(p1) << 16);
      }
    rs += __shfl_xor(rs, 16, 64);
    rs += __shfl_xor(rs, 32, 64);
    if (__any(grow)) {
      float sf = __expf(mrow - newm);
      lrow = lrow * sf + rs;
#pragma unroll
      for (int r = 0; r < 4; r++) {
        float sfb = __shfl(sf, lg * 4 + r, 64);
#pragma unroll
        for (int di = 0; di < 4; di++) o[di][r] *= sfb;
      }
    } else {
      lrow += rs;
    }
    mrow = newm;

    // P -> per-wave LDS (packed dwords, b64 stores), then read back as A-frags
#pragma unroll
    for (int ji = 0; ji < 4; ji++)
      *(uint2*)&lsPw[lr * 36 + ji * 8 + lg * 2] = make_uint2(pd[2 * ji], pd[2 * ji + 1]);
#pragma unroll
    for (int js = 0; js < 2; js++) {
      bf16x8 pa = *(const bf16x8*)&lsPw[lr * 36 + js * 16 + lg * 4];
#pragma unroll
      for (int di = 0; di < 4; di++) {
        int drow = di * 16 + lr;
        bf16x8 vb = *(const bf16x8*)&lsV[drow * 64 + ((js * 32 + lg * 8) ^ ((drow & 7) * 8))];
        o[di] = __builtin_amdgcn_mfma_f32_16x16x32_bf16(pa, vb, o[di], 0, 0, 0);
      }
    }
  }

  const int b = bh >> 4, h = bh & 15;
  float inv = 1.f / lrow;
#pragma unroll
  for (int r = 0; r < 4; r++) {
    float invb = __shfl(inv, lg * 4 + r, 64);
#pragma unroll
    for (int di = 0; di < 4; di++) {
      long rowt = (long)(b * T_ + qt * 64 + w * 16 + lg * 4 + r);
      O[rowt * 1024 + h * 64 + di * 16 + lr] = f2bf(o[di][r] * invb);
    }
  }
}

extern "C" void kernel_launch(void* const* d_in, const int* in_sizes, int n_in,
                              void* d_out, int out_size, void* d_ws, size_t ws_size,
                              hipStream_t stream) {
  (void)in_sizes; (void)n_in; (void)out_size; (void)ws_size;
  const float* x     = (const float*)d_in[0];
  // d_in[1] = mask: deterministic causal triu — applied analytically, not read.
  const float* qkv_w = (const float*)d_in[2];
  const float* qkv_b = (const float*)d_in[3];
  const float* out_w = (const float*)d_in[4];
  const float* out_b = (const float*)d_in[5];
  char* ws = (char*)d_ws;
  size_t off = 0;
  auto alloc = [&](size_t n) { void* p = ws + off; off += (n + 255) & ~(size_t)255; return p; };
  u16*   xb    = (u16*)alloc((size_t)M_ * HID * 2);
  u16*   wqkv  = (u16*)alloc((size_t)NQKV * HID * 2);
  u16*   wout  = (u16*)alloc((size_t)HID * HID * 2);
  u16*   qkvb  = (u16*)alloc((size_t)M_ * NQKV * 2);
  u16*   Qb    = (u16*)alloc((size_t)M_ * HID * 2);
  u16*   Kb    = (u16*)alloc((size_t)M_ * HID * 2);
  u16*   Vtb   = (u16*)alloc((size_t)M_ * HID * 2);
  u16*   attnb = (u16*)alloc((size_t)M_ * HID * 2);
  float* tab   = (float*)alloc((size_t)T_ * 16 * 2 * 4);

  rope_tab<<<T_ * 16 / 256, 256, 0, stream>>>(tab);
  cvt_bf16<<<(M_ * HID / 4 + 255) / 256, 256, 0, stream>>>(x, xb, M_ * HID / 4);
  cvt_bf16<<<(NQKV * HID / 4 + 255) / 256, 256, 0, stream>>>(qkv_w, wqkv, NQKV * HID / 4);
  cvt_bf16<<<(HID * HID / 4 + 255) / 256, 256, 0, stream>>>(out_w, wout, HID * HID / 4);
  gemm_nt<1><<<dim3(NQKV / 128, M_ / 128), 256, 0, stream>>>(xb, wqkv, qkv_b, qkvb, NQKV, HID);
  rope_qk<<<(B_ * T_ * H_) / 256, 256, 0, stream>>>(qkvb, tab, Qb, Kb);
  v_trans<<<dim3(T_ / 64, B_ * H_), 256, 0, stream>>>(qkvb, Vtb);
  fattn<<<1024, 256, 0, stream>>>(Qb, Kb, Vtb, attnb);
  gemm_nt<0><<<dim3(HID / 128, M_ / 128), 256, 0, stream>>>(attnb, wout, out_b, (float*)d_out, HID, HID);
}

// Round 3
// 210.745 us; speedup vs baseline: 1.5920x; 1.0599x over previous
//
#include <hip/hip_runtime.h>
#include <math.h>

typedef unsigned short u16;
typedef unsigned int u32;
typedef __attribute__((ext_vector_type(4))) float f32x4;
typedef __attribute__((ext_vector_type(8))) short bf16x8;

#define B_ 2
#define T_ 2048
#define H_ 16
#define HID 1024
#define NQKV 3072
#define M_ 4096
#define SCALE_Q 0.18033688011112042f /* 0.125 * log2(e): softmax done in exp2 domain */

__device__ __forceinline__ u16 f2bf(float f) {
  union { float f; unsigned u; } v; v.f = f;
  unsigned r = v.u + 0x7FFFu + ((v.u >> 16) & 1u);
  return (u16)(r >> 16);
}
__device__ __forceinline__ float bf2f(u16 u) {
  union { unsigned u; float f; } v; v.u = ((unsigned)u) << 16; return v.f;
}
__device__ __forceinline__ u32 cvt_pk_bf16(float lo, float hi) {
  u32 r;
  asm("v_cvt_pk_bf16_f32 %0, %1, %2" : "=v"(r) : "v"(lo), "v"(hi));
  return r;
}
__device__ __forceinline__ float fexp2(float x) { return __builtin_amdgcn_exp2f(x); }

// async global->LDS, 16B per lane; LDS dest = wave-uniform base + lane*16
__device__ __forceinline__ void gload16(const void* g, void* l) {
  __builtin_amdgcn_global_load_lds((const __attribute__((address_space(1))) void*)g,
                                   (__attribute__((address_space(3))) void*)l, 16, 0, 0);
}

// ---------------- prep: rope table + 3x fp32->bf16 convert, fused ----------------
__global__ void prep(const float* __restrict__ x, const float* __restrict__ qkv_w,
                     const float* __restrict__ out_w, u16* __restrict__ xb,
                     u16* __restrict__ wqkv, u16* __restrict__ wout, float* __restrict__ tab) {
  int bid = blockIdx.x;
  if (bid < 128) {  // rope table: tab[t*16+f] = {cos, sin}
    int i = bid * 256 + threadIdx.x;
    int tpos = i >> 4, f = i & 15;
    float ang = (float)tpos * exp2f(-(float)f * 0.83048202372184058696f);
    float s, c;
    sincosf(ang, &s, &c);
    tab[i * 2] = c;
    tab[i * 2 + 1] = s;
    return;
  }
  bid -= 128;
  const float* in;
  u16* out;
  if (bid < 4096) { in = x; out = xb; }
  else if (bid < 7168) { bid -= 4096; in = qkv_w; out = wqkv; }
  else { bid -= 7168; in = out_w; out = wout; }
  int i = bid * 256 + threadIdx.x;
  float4 v = ((const float4*)in)[i];
  uint2 o;
  o.x = (unsigned)f2bf(v.x) | ((unsigned)f2bf(v.y) << 16);
  o.y = (unsigned)f2bf(v.z) | ((unsigned)f2bf(v.w) << 16);
  ((uint2*)out)[i] = o;
}

// ---------------- NT GEMM, dbuf-prefetch (T3-min): C = A.Bt^T + bias ----------------
// A:[M][K], Bt:[N][K] bf16. Tile BM x 128, BK=32, 4 waves as WROWS x (4/WROWS).
template<int BM, int WROWS, int OUT_BF16>
__global__ __launch_bounds__(256) void gemm_nt(const u16* __restrict__ A,
    const u16* __restrict__ Bt, const float* __restrict__ bias,
    void* __restrict__ outp, int N, int K)
{
  constexpr int WCOLS = 4 / WROWS;
  constexpr int MI = BM / WROWS / 16;
  constexpr int NI = 128 / WCOLS / 16;
  __shared__ u16 lsA[2][BM * 32];
  __shared__ u16 lsB[2][128 * 32];
  const int t = threadIdx.x;
  const int l = t & 63, w = t >> 6;
  const int wm = (w / WCOLS) * (BM / WROWS);
  const int wn = (w % WCOLS) * (128 / WCOLS);
  const int lr = l & 15, lg = l >> 4;
  const long bm = (long)blockIdx.y * BM, bn = (long)blockIdx.x * 128;

  f32x4 acc[MI][NI];
#pragma unroll
  for (int i = 0; i < MI; i++)
#pragma unroll
    for (int j = 0; j < NI; j++) acc[i][j] = (f32x4){0.f, 0.f, 0.f, 0.f};

  // staging: slab = 16 rows x 32 k = 1KB = one wave-wide gload16
  const int srow = l >> 2, sko = (l & 3) * 8;
  const u16* Ab = A + (bm + srow) * (long)K + sko;
  const u16* Bb = Bt + (bn + srow) * (long)K + sko;

  auto stage = [&](int buf, int k0) {
    gload16(Ab + (long)(w * 16) * K + k0, &lsA[buf][w * 512]);
    if constexpr (BM == 128)
      gload16(Ab + (long)((w + 4) * 16) * K + k0, &lsA[buf][(w + 4) * 512]);
    gload16(Bb + (long)(w * 16) * K + k0, &lsB[buf][w * 512]);
    gload16(Bb + (long)((w + 4) * 16) * K + k0, &lsB[buf][(w + 4) * 512]);
  };

  stage(0, 0);
  __syncthreads();  // drains vmcnt(0): tile 0 landed
  int cur = 0;
  for (int k0 = 0; k0 < K; k0 += 32) {
    if (k0 + 32 < K) stage(cur ^ 1, k0 + 32);  // prefetch overlaps compute below
    bf16x8 af[MI], bfv[NI];
#pragma unroll
    for (int mi = 0; mi < MI; mi++)
      af[mi] = *(const bf16x8*)&lsA[cur][(wm + mi * 16 + lr) * 32 + lg * 8];
#pragma unroll
    for (int ni = 0; ni < NI; ni++)
      bfv[ni] = *(const bf16x8*)&lsB[cur][(wn + ni * 16 + lr) * 32 + lg * 8];
    __builtin_amdgcn_s_setprio(1);
#pragma unroll
    for (int mi = 0; mi < MI; mi++)
#pragma unroll
      for (int ni = 0; ni < NI; ni++)
        acc[mi][ni] = __builtin_amdgcn_mfma_f32_16x16x32_bf16(af[mi], bfv[ni], acc[mi][ni], 0, 0, 0);
    __builtin_amdgcn_s_setprio(0);
    __syncthreads();  // vmcnt(0)+barrier: prefetch landed, reads done before overwrite
    cur ^= 1;
  }
#pragma unroll
  for (int mi = 0; mi < MI; mi++)
#pragma unroll
    for (int ni = 0; ni < NI; ni++) {
      long row = bm + wm + mi * 16 + lg * 4;
      long col = bn + wn + ni * 16 + lr;
      float bv = bias[col];
#pragma unroll
      for (int r = 0; r < 4; r++) {
        float v = acc[mi][ni][r] + bv;
        if (OUT_BF16) ((u16*)outp)[(row + r) * (long)N + col] = f2bf(v);
        else          ((float*)outp)[(row + r) * (long)N + col] = v;
      }
    }
}

// ---------------- post_qkv: RoPE(q,k) + V transpose, fused ----------------
// blocks [0,256): rope; blocks [256,1280): v_trans
__global__ __launch_bounds__(256) void post_qkv(const u16* __restrict__ qkv,
    const float* __restrict__ tab, u16* __restrict__ Q, u16* __restrict__ K,
    u16* __restrict__ Vt) {
  __shared__ u16 ls[64 * 72];
  const int bid = blockIdx.x;
  if (bid < 256) {
    int idx = bid * 256 + threadIdx.x;  // one thread per (m, h)
    int h = idx & 15;
    int m = idx >> 4;
    int tpos = m & (T_ - 1);
    int b = m >> 11;
    const u16* qr = qkv + (long)m * NQKV + h * 64;
    alignas(16) u16 qv[64];
    alignas(16) u16 kv[64];
#pragma unroll
    for (int c = 0; c < 8; c++) {
      *(int4*)&qv[c * 8] = *(const int4*)&qr[c * 8];
      *(int4*)&kv[c * 8] = *(const int4*)&qr[1024 + c * 8];
    }
#pragma unroll
    for (int i = 0; i < 16; i++) {
      float c = tab[(tpos * 16 + i) * 2];
      float s = tab[(tpos * 16 + i) * 2 + 1];
      float q1 = bf2f(qv[2 * i]), q2 = bf2f(qv[2 * i + 1]);
      qv[2 * i]     = f2bf((q1 * c - q2 * s) * SCALE_Q);
      qv[2 * i + 1] = f2bf((q1 * s + q2 * c) * SCALE_Q);
      float k1 = bf2f(kv[2 * i]), k2 = bf2f(kv[2 * i + 1]);
      kv[2 * i]     = f2bf(k1 * c - k2 * s);
      kv[2 * i + 1] = f2bf(k1 * s + k2 * c);
    }
#pragma unroll
    for (int j = 32; j < 64; j++) qv[j] = f2bf(bf2f(qv[j]) * SCALE_Q);
    long ob = ((long)(b * 16 + h) * T_ + tpos) * 64;
#pragma unroll
    for (int c = 0; c < 8; c++) {
      *(int4*)&Q[ob + c * 8] = *(int4*)&qv[c * 8];
      *(int4*)&K[ob + c * 8] = *(int4*)&kv[c * 8];
    }
  } else {
    int id2 = bid - 256;
    int tt = id2 & 31, bh = id2 >> 5;
    int b = bh >> 4, h = bh & 15;
    int t = threadIdx.x;
    for (int c = t; c < 512; c += 256) {
      int row = c >> 3, off = (c & 7) * 8;
      *(int4*)&ls[row * 72 + off] =
          *(const int4*)&qkv[((long)(b * T_ + tt * 64 + row)) * NQKV + 2048 + h * 64 + off];
    }
    __syncthreads();
    for (int c = t; c < 512; c += 256) {
      int d = c >> 3, toff = (c & 7) * 8;
      alignas(16) u16 tmp[8];
#pragma unroll
      for (int j = 0; j < 8; j++) tmp[j] = ls[(toff + j) * 72 + d];
      *(int4*)&Vt[((long)(bh * 64 + d)) * T_ + tt * 64 + toff] = *(int4*)tmp;
    }
  }
}

// ---------------- causal flash attention, swapped-QK^T, dbuf prefetch ----------------
// 1024 blocks (heavy qt first), 4 waves; wave w owns q-rows [qt*64+w*16, +16).
__global__ __launch_bounds__(256, 4) void fattn(const u16* __restrict__ Q, const u16* __restrict__ Kp,
                                                const u16* __restrict__ V, u16* __restrict__ O) {
  const int id = blockIdx.x;
  const int qt = 31 - (id >> 5);  // heavy blocks dispatched first
  const int bh = id & 31;
  __shared__ u16 lsK[2][64 * 64];  // [krow][d], XOR swizzle: u16 chunk ^= (row&7)
  __shared__ u16 lsV[2][64 * 64];  // [d][k], same swizzle
  __shared__ u32 lsP[4][16 * 36];  // per-wave P round-trip
  const int t = threadIdx.x, l = t & 63, w = t >> 6;
  const int lr = l & 15, lg = l >> 4;
  const u16* Qb = Q + (long)bh * T_ * 64;
  const u16* Kb = Kp + (long)bh * T_ * 64;
  const u16* Vb = V + (long)bh * 64 * T_;
  u32* lsPw = lsP[w];

  bf16x8 aq[2];  // B-frag: Q rows (pre-scaled by 0.125*log2e)
#pragma unroll
  for (int ks = 0; ks < 2; ks++)
    aq[ks] = *(const bf16x8*)&Qb[((long)(qt * 64 + w * 16 + lr)) * 64 + ks * 32 + lg * 8];

  f32x4 o[4];
#pragma unroll
  for (int di = 0; di < 4; di++) o[di] = (f32x4){0.f, 0.f, 0.f, 0.f};
  float mrow = -1e30f, lrow = 0.f;

  // staging: slab = 8 rows x 128B; wave w stages slabs {2w,2w+1} of K and V.
  // pre-swizzled global source (m173): LDS chunk c holds src chunk c^(row&7).
  const int srow = l >> 3;
  const int scx = ((l & 7) ^ srow) * 8;
  const long kgo0 = (long)(16 * w + srow) * 64 + scx;
  const long kgo1 = (long)(16 * w + 8 + srow) * 64 + scx;
  const long vgo0 = (long)(16 * w + srow) * T_ + scx;
  const long vgo1 = (long)(16 * w + 8 + srow) * T_ + scx;

  gload16(Kb + kgo0, &lsK[0][(2 * w) * 512]);
  gload16(Kb + kgo1, &lsK[0][(2 * w + 1) * 512]);
  gload16(Vb + vgo0, &lsV[0][(2 * w) * 512]);
  gload16(Vb + vgo1, &lsV[0][(2 * w + 1) * 512]);
  __syncthreads();  // vmcnt(0) drain: tile 0 ready

  int cur = 0;
  for (int kt = 0; kt <= qt; kt++) {
    if (kt < qt) {  // prefetch next tile; lands by the end-of-iter barrier
      const u16* kp = Kb + (kt + 1) * 4096;
      const u16* vp = Vb + (kt + 1) * 64;
      gload16(kp + kgo0, &lsK[cur ^ 1][(2 * w) * 512]);
      gload16(kp + kgo1, &lsK[cur ^ 1][(2 * w + 1) * 512]);
      gload16(vp + vgo0, &lsV[cur ^ 1][(2 * w) * 512]);
      gload16(vp + vgo1, &lsV[cur ^ 1][(2 * w + 1) * 512]);
    }

    // S^T = K . Q^T : s[ji] rows k=ji*16+lg*4+r, col q=lr
    f32x4 s[4];
#pragma unroll
    for (int ji = 0; ji < 4; ji++) s[ji] = (f32x4){0.f, 0.f, 0.f, 0.f};
    __builtin_amdgcn_s_setprio(1);
#pragma unroll
    for (int ks = 0; ks < 2; ks++)
#pragma unroll
      for (int ji = 0; ji < 4; ji++) {
        int row = ji * 16 + lr;
        bf16x8 kf = *(const bf16x8*)&lsK[cur][row * 64 + ((ks * 32 + lg * 8) ^ ((row & 7) * 8))];
        s[ji] = __builtin_amdgcn_mfma_f32_16x16x32_bf16(kf, aq[ks], s[ji], 0, 0, 0);
      }
    __builtin_amdgcn_s_setprio(0);

    if (kt == qt) {  // diagonal tile only
      int qloc = w * 16 + lr;
#pragma unroll
      for (int ji = 0; ji < 4; ji++)
#pragma unroll
        for (int r = 0; r < 4; r++)
          if (ji * 16 + lg * 4 + r > qloc) s[ji][r] = -1e30f;
    }

    float mx = s[0][0];
#pragma unroll
    for (int ji = 0; ji < 4; ji++)
#pragma unroll
      for (int r = 0; r < 4; r++) mx = fmaxf(mx, s[ji][r]);
    mx = fmaxf(mx, __shfl_xor(mx, 16, 64));
    mx = fmaxf(mx, __shfl_xor(mx, 32, 64));

    if (__any(mx - mrow > 8.f)) {  // defer-max (T13): rescale only on real growth
      float newm = fmaxf(mrow, mx);
      float sf = fexp2(mrow - newm);
      mrow = newm;
      lrow *= sf;
#pragma unroll
      for (int r = 0; r < 4; r++) {
        float sfb = __shfl(sf, lg * 4 + r, 64);
#pragma unroll
        for (int di = 0; di < 4; di++) o[di][r] *= sfb;
      }
    }

    float rs = 0.f;
    u32 pd[8];
#pragma unroll
    for (int ji = 0; ji < 4; ji++)
#pragma unroll
      for (int hh = 0; hh < 2; hh++) {
        float p0 = fexp2(s[ji][2 * hh] - mrow);
        float p1 = fexp2(s[ji][2 * hh + 1] - mrow);
        rs += p0 + p1;
        pd[ji * 2 + hh] = cvt_pk_bf16(p0, p1);
      }
    rs += __shfl_xor(rs, 16, 64);
    rs += __shfl_xor(rs, 32, 64);
    lrow += rs;

    // P -> per-wave LDS (packed b64 stores), read back as PV A-frags
#pragma unroll
    for (int ji = 0; ji < 4; ji++)
      *(uint2*)&lsPw[lr * 36 + ji * 8 + lg * 2] = make_uint2(pd[2 * ji], pd[2 * ji + 1]);
    __builtin_amdgcn_s_setprio(1);
#pragma unroll
    for (int js = 0; js < 2; js++) {
      bf16x8 pa = *(const bf16x8*)&lsPw[lr * 36 + js * 16 + lg * 4];
#pragma unroll
      for (int di = 0; di < 4; di++) {
        int drow = di * 16 + lr;
        bf16x8 vb = *(const bf16x8*)&lsV[cur][drow * 64 + ((js * 32 + lg * 8) ^ ((drow & 7) * 8))];
        o[di] = __builtin_amdgcn_mfma_f32_16x16x32_bf16(pa, vb, o[di], 0, 0, 0);
      }
    }
    __builtin_amdgcn_s_setprio(0);

    if (kt < qt) __syncthreads();  // drain prefetch + guard buffer reuse
    cur ^= 1;
  }

  const int b = bh >> 4, h = bh & 15;
  float inv = 1.f / lrow;
#pragma unroll
  for (int r = 0; r < 4; r++) {
    float invb = __shfl(inv, lg * 4 + r, 64);
#pragma unroll
    for (int di = 0; di < 4; di++) {
      long rowt = (long)(b * T_ + qt * 64 + w * 16 + lg * 4 + r);
      O[rowt * 1024 + h * 64 + di * 16 + lr] = f2bf(o[di][r] * invb);
    }
  }
}

extern "C" void kernel_launch(void* const* d_in, const int* in_sizes, int n_in,
                              void* d_out, int out_size, void* d_ws, size_t ws_size,
                              hipStream_t stream) {
  (void)in_sizes; (void)n_in; (void)out_size; (void)ws_size;
  const float* x     = (const float*)d_in[0];
  // d_in[1] = mask: deterministic causal triu — applied analytically, not read.
  const float* qkv_w = (const float*)d_in[2];
  const float* qkv_b = (const float*)d_in[3];
  const float* out_w = (const float*)d_in[4];
  const float* out_b = (const float*)d_in[5];
  char* ws = (char*)d_ws;
  size_t off = 0;
  auto alloc = [&](size_t n) { void* p = ws + off; off += (n + 255) & ~(size_t)255; return p; };
  u16*   xb    = (u16*)alloc((size_t)M_ * HID * 2);
  u16*   wqkv  = (u16*)alloc((size_t)NQKV * HID * 2);
  u16*   wout  = (u16*)alloc((size_t)HID * HID * 2);
  u16*   qkvb  = (u16*)alloc((size_t)M_ * NQKV * 2);
  u16*   Qb    = (u16*)alloc((size_t)M_ * HID * 2);
  u16*   Kb    = (u16*)alloc((size_t)M_ * HID * 2);
  u16*   Vtb   = (u16*)alloc((size_t)M_ * HID * 2);
  u16*   attnb = (u16*)alloc((size_t)M_ * HID * 2);
  float* tab   = (float*)alloc((size_t)T_ * 16 * 2 * 4);

  prep<<<8320, 256, 0, stream>>>(x, qkv_w, out_w, xb, wqkv, wout, tab);
  gemm_nt<128, 2, 1><<<dim3(NQKV / 128, M_ / 128), 256, 0, stream>>>(xb, wqkv, qkv_b, qkvb, NQKV, HID);
  post_qkv<<<1280, 256, 0, stream>>>(qkvb, tab, Qb, Kb, Vtb);
  fattn<<<1024, 256, 0, stream>>>(Qb, Kb, Vtb, attnb);
  gemm_nt<64, 1, 0><<<dim3(HID / 128, M_ / 64), 256, 0, stream>>>(attnb, wout, out_b, (float*)d_out, HID, HID);
}